// Round 3
// baseline (648.515 us; speedup 1.0000x reference)
//
#include <hip/hip_runtime.h>

// low_rank multimodal fusion: B=131072, IN=128 (+bias row -> K=129), OUT=128, RANK=4.
// out[b,o] = bias[o] + sum_r w[r] * prod_m ( factor_m[r,0,o] + sum_k x[b,m,k]*factor_m[r,k+1,o] )
// R2: B-fragments staged per-ot into LDS via global_load_lds width=16; MFMA reads LDS.
// R4: double-buffered half-ot pipeline, counted vmcnt, waves_per_eu(2,2) -> ~118 us, all
//     pipes <50% busy: concurrency-starved at 2 blocks/CU (8 waves).
// R5: (a) factor-bias rows in LDS as f16 (same rounding the other 128 factor rows already
//         get in pack_b); fb stays f32. LDS 54.6 -> 51.5 KB => 3 blocks/CU (12 waves,
//         3/SIMD) with waves_per_eu(3) (budget ~168 >= hard-live ~130: A96+acc24+oacc8).
//     (b) stores moved AFTER ISSUE(ot+1,1): no wait ever retires a store (the old h0
//         vmcnt(12) forced 10 nt-store retirements = HBM write-latency convoy).
//         Ledger (6 gload_lds per half-group, 16 stores per ot, in-order retirement):
//           h0-wait of ot:   [L(ot,0)6, L(ot,1)6, S(ot-1)16] = 28 -> vmcnt(22) retires
//                            exactly L(ot,0).  ot==0: [6,6]=12 -> vmcnt(6).
//           h1-wait of ot:   [L(ot,1)6, S(ot-1)16, L(ot+1,0)6] = 28 -> vmcnt(22) retires
//                            exactly L(ot,1).  ot==0: vmcnt(6).  ot==7: [6,16]=22 -> vmcnt(16).
//     (c) ISSUE(0,*) moved BEFORE the x-prologue: first tiles' L2 latency hides under the
//         prologue (ledger-safe: all x-loads are consumed by converts before the loop, and
//         in-order retirement means they are fully retired by loop entry).

typedef _Float16 half8 __attribute__((ext_vector_type(8)));
typedef float f32x4 __attribute__((ext_vector_type(4)));

#define NB 131072L
#define OUT_OFF (NB * 128L)

static __device__ inline f32x4 splat4(float s) { return (f32x4){s, s, s, s}; }
#define CFENCE() asm volatile("" ::: "memory")

// ---------------- prep: pack factors (fp32, [r,129,128]) into f16 MFMA-B fragments ----
// packed frag index: ((m*4 + r)*8 + ot)*4 + ks ; within frag: lane-major, 8 halfs/lane.
// B-frag lane mapping (16x16x32): n = lane&15, k = (lane>>4)*8 + j  (factor row = k+1).
__global__ void pack_b_kernel(const float* __restrict__ af, const float* __restrict__ vf,
                              const float* __restrict__ tf, _Float16* __restrict__ bpk) {
  int t = blockIdx.x * 256 + threadIdx.x;  // [0, 24576)
  int l = t & 63;
  int ks = (t >> 6) & 3;
  int ot = (t >> 8) & 7;
  int r = (t >> 11) & 3;
  int m = t >> 13;
  const float* f = (m == 0) ? af : ((m == 1) ? vf : tf);
  int i0 = 1 + ks * 32 + (l >> 4) * 8;
  int o = ot * 16 + (l & 15);
  half8 v;
#pragma unroll
  for (int j = 0; j < 8; ++j) v[j] = (_Float16)f[(r * 129 + i0 + j) * 128 + o];
  *(half8*)(bpk + (size_t)t * 8) = v;
}

// issue one half-group: 6 regions i = mod*4 + 2h + rr (il = mod*2 + rr), 4 KB each,
// block covers each region in one pass; LDS dst = wave-uniform base + lane*16 (HW layout).
#define ISSUE(ot_, h_)                                                                     \
  do {                                                                                     \
    _Pragma("unroll") for (int il = 0; il < 6; ++il) {                                     \
      const int i_ = (il >> 1) * 4 + 2 * (h_) + (il & 1);                                  \
      const _Float16* gp = bpk + (size_t)(((i_ * 8 + (ot_)) * 2048) + wv * 512 + lane * 8);\
      _Float16* lp = bl + ((h_)*12288 + il * 2048 + wv * 512 + lane * 8);                  \
      __builtin_amdgcn_global_load_lds((const __attribute__((address_space(1))) void*)gp,  \
                                       (__attribute__((address_space(3))) void*)lp, 16, 0, \
                                       0);                                                 \
    }                                                                                      \
  } while (0)

// compute one half: ranks r = 2h, 2h+1 fully (all 3 mods), products folded into oacc
#define COMPUTE_HALF(h_)                                                                   \
  do {                                                                                     \
    _Pragma("unroll") for (int rr = 0; rr < 2; ++rr) {                                     \
      const int r_ = 2 * (h_) + rr;                                                        \
      f32x4 acc[3][2];                                                                     \
      _Pragma("unroll") for (int mod = 0; mod < 3; ++mod) {                                \
        acc[mod][0] = splat4((float)bias_h[mod * 512 + r_ * 128 + ocol]);                  \
        acc[mod][1] = acc[mod][0];                                                         \
      }                                                                                    \
      __builtin_amdgcn_s_setprio(1);                                                       \
      _Pragma("unroll") for (int mod = 0; mod < 3; ++mod) {                                \
        const _Float16* bb = bl + (h_)*12288 + (mod * 2 + rr) * 2048 + lane * 8;           \
        _Pragma("unroll") for (int ks = 0; ks < 4; ++ks) {                                 \
          half8 bf = *(const half8*)(bb + ks * 512); /* ds_read_b128, conflict-free */     \
          acc[mod][0] =                                                                    \
              __builtin_amdgcn_mfma_f32_16x16x32_f16(a[0][mod][ks], bf, acc[mod][0], 0, 0, \
                                                     0);                                   \
          acc[mod][1] =                                                                    \
              __builtin_amdgcn_mfma_f32_16x16x32_f16(a[1][mod][ks], bf, acc[mod][1], 0, 0, \
                                                     0);                                   \
        }                                                                                  \
      }                                                                                    \
      __builtin_amdgcn_s_setprio(0);                                                       \
      _Pragma("unroll") for (int mt = 0; mt < 2; ++mt) {                                   \
        _Pragma("unroll") for (int g = 0; g < 4; ++g) {                                    \
          oacc[mt][g] += wr[r_] * (acc[0][mt][g] * acc[1][mt][g] * acc[2][mt][g]);         \
        }                                                                                  \
      }                                                                                    \
    }                                                                                      \
  } while (0)

// ---------------- main fused kernel -------------------------------------------------
// grid: 1024 blocks x 256 threads; wave W = blockIdx*4 + (tid>>6) owns rows [W*32, W*32+32)
__global__ __launch_bounds__(256) __attribute__((amdgpu_waves_per_eu(3))) void lmf_main(
    const float* __restrict__ x, const float* __restrict__ af, const float* __restrict__ vf,
    const float* __restrict__ tf, const float* __restrict__ fw, const float* __restrict__ fb,
    const _Float16* __restrict__ bpk, float* __restrict__ out) {
  __shared__ _Float16 bl[2 * 12288];  // 2 x 24 KB: buf h holds ranks {2h, 2h+1} of one ot
  __shared__ _Float16 bias_h[1536];   // factor bias rows, f16: [mod*512 + r*128 + o]
  __shared__ float fb_l[128];         // fusion bias, kept f32 (absmax is at the edge)

  const int lane = threadIdx.x & 63;
  const int wv = threadIdx.x >> 6;
  const int W = blockIdx.x * 4 + wv;
  const long row0 = (long)W * 32;
  const int m16 = lane & 15;  // A row within tile / C col
  const int q = lane >> 4;    // k-octet selector / C row-quad

  // ---- one-time bias staging (loop body then reads LDS only: no stray VMEM in ledger) ----
  for (int idx = threadIdx.x; idx < 1536; idx += 256) {
    const int mod = idx >> 9, rem = idx & 511;
    const float* f = (mod == 0) ? af : ((mod == 1) ? vf : tf);
    bias_h[idx] = (_Float16)f[(rem >> 7) * 16512 + (rem & 127)];
  }
  if (threadIdx.x < 128) fb_l[threadIdx.x] = fb[threadIdx.x];
  __syncthreads();  // full drain: ledger starts clean

  // ---- start the pipeline BEFORE the x-prologue: staging rides under prologue latency ----
  CFENCE();
  ISSUE(0, 0);
  ISSUE(0, 1);
  CFENCE();

  // ---- A fragments: a[mt][mod][ks], 8 halfs each (96 VGPRs), fp32->fp16 RTN ----
  half8 a[2][3][4];
#pragma unroll
  for (int mt = 0; mt < 2; ++mt) {
    const float* xs = x + (row0 + mt * 16 + m16) * 384 + q * 8;
#pragma unroll
    for (int mod = 0; mod < 3; ++mod) {
#pragma unroll
      for (int ks = 0; ks < 4; ++ks) {
        const float* p = xs + mod * 128 + ks * 32;
        f32x4 p0 = __builtin_nontemporal_load((const f32x4*)p);
        f32x4 p1 = __builtin_nontemporal_load((const f32x4*)(p + 4));
#pragma unroll
        for (int j = 0; j < 4; ++j) {
          a[mt][mod][ks][j] = (_Float16)p0[j];
          a[mt][mod][ks][4 + j] = (_Float16)p1[j];
        }
      }
    }
  }
  // pin A resident: compiler cannot rematerialize a[] from x inside the ot loop
#pragma unroll
  for (int mt = 0; mt < 2; ++mt)
#pragma unroll
    for (int mod = 0; mod < 3; ++mod)
#pragma unroll
      for (int ks = 0; ks < 4; ++ks) asm volatile("" : "+v"(a[mt][mod][ks]));

  const float wr[4] = {fw[0], fw[1], fw[2], fw[3]};  // wave-uniform -> SGPRs

  float* po0 = out + (row0 + q * 4) * 128 + m16;       // mt=0, copy 0
  float* po1 = out + (row0 + 16 + q * 4) * 128 + m16;  // mt=1, copy 0
  float* qo0 = po0 + OUT_OFF;                          // copy 1
  float* qo1 = po1 + OUT_OFF;

#pragma unroll 1
  for (int ot = 0; ot < 8; ++ot) {
    const int ocol = ot * 16 + m16;

    // ================= half 0 : ranks 0,1 (buf 0) =================
    if (ot == 0) {
      asm volatile("s_waitcnt vmcnt(6)" ::: "memory");  // retire L(0,0); L(0,1) in flight
    } else {
      asm volatile("s_waitcnt vmcnt(22)" ::: "memory");  // retire exactly L(ot,0); no stores
    }
    __builtin_amdgcn_s_barrier();  // all waves' buf0 quarters landed
    CFENCE();
    f32x4 oacc[2];
    oacc[0] = splat4(fb_l[ocol]);
    oacc[1] = oacc[0];
    COMPUTE_HALF(0);
    CFENCE();
    __builtin_amdgcn_s_barrier();  // all waves done reading buf0
    CFENCE();
    if (ot < 7) ISSUE(ot + 1, 0);  // overwrite buf0 with next ot's r{0,1}

    // ================= half 1 : ranks 2,3 (buf 1) =================
    if (ot == 0) {
      asm volatile("s_waitcnt vmcnt(6)" ::: "memory");  // retire L(0,1); L(1,0) in flight
    } else if (ot < 7) {
      asm volatile("s_waitcnt vmcnt(22)" ::: "memory");  // retire exactly L(ot,1)
    } else {
      asm volatile("s_waitcnt vmcnt(16)" ::: "memory");  // [L(7,1)6, S(6)16]: retire L(7,1)
    }
    __builtin_amdgcn_s_barrier();
    CFENCE();
    COMPUTE_HALF(1);
    CFENCE();
    __builtin_amdgcn_s_barrier();  // all waves done reading buf1
    CFENCE();
    if (ot < 7) ISSUE(ot + 1, 1);  // overwrite buf1 with next ot's r{2,3}

    // stores AFTER the re-issue: they enter the ledger newest, and no wait retires them.
    // C/D layout: col = lane&15, row = q*4 + g
#pragma unroll
    for (int g = 0; g < 4; ++g) {
      __builtin_nontemporal_store(oacc[0][g], po0 + ot * 16 + g * 128);
      __builtin_nontemporal_store(oacc[1][g], po1 + ot * 16 + g * 128);
      __builtin_nontemporal_store(oacc[0][g], qo0 + ot * 16 + g * 128);
      __builtin_nontemporal_store(oacc[1][g], qo1 + ot * 16 + g * 128);
    }
    CFENCE();
  }
}

// ---------------- fallback (only if d_ws is too small): correct fp32 vector version --
__global__ void lmf_fallback(const float* __restrict__ x, const float* __restrict__ af,
                             const float* __restrict__ vf, const float* __restrict__ tf,
                             const float* __restrict__ fw, const float* __restrict__ fb,
                             float* __restrict__ out) {
  long b = blockIdx.x;
  int o = threadIdx.x;  // 128 threads
  __shared__ float xr[384];
  for (int i = threadIdx.x; i < 384; i += 128) xr[i] = x[b * 384 + i];
  __syncthreads();
  float acc = fb[o];
  for (int r = 0; r < 4; ++r) {
    const float* A = af + (long)r * 16512 + o;
    const float* V = vf + (long)r * 16512 + o;
    const float* T = tf + (long)r * 16512 + o;
    float sa = A[0], sv = V[0], st = T[0];
    for (int i = 0; i < 128; ++i) {
      sa += xr[i] * A[(i + 1) * 128];
      sv += xr[128 + i] * V[(i + 1) * 128];
      st += xr[256 + i] * T[(i + 1) * 128];
    }
    acc += fw[r] * sa * sv * st;
  }
  out[b * 128 + o] = acc;
  out[OUT_OFF + b * 128 + o] = acc;
}

extern "C" void kernel_launch(void* const* d_in, const int* in_sizes, int n_in, void* d_out,
                              int out_size, void* d_ws, size_t ws_size, hipStream_t stream) {
  const float* x = (const float*)d_in[0];
  const float* af = (const float*)d_in[1];
  const float* vf = (const float*)d_in[2];
  const float* tf = (const float*)d_in[3];
  const float* fw = (const float*)d_in[4];
  const float* fb = (const float*)d_in[5];
  float* out = (float*)d_out;

  const size_t need = 24576 * 8 * sizeof(_Float16);  // 384 KiB packed B
  if (ws_size >= need) {
    pack_b_kernel<<<96, 256, 0, stream>>>(af, vf, tf, (_Float16*)d_ws);
    lmf_main<<<1024, 256, 0, stream>>>(x, af, vf, tf, fw, fb, (const _Float16*)d_ws, out);
  } else {
    lmf_fallback<<<dim3(131072), 128, 0, stream>>>(x, af, vf, tf, fw, fb, out);
  }
}

// Round 4
// 411.146 us; speedup vs baseline: 1.5773x; 1.5773x over previous
//
#include <hip/hip_runtime.h>

// low_rank multimodal fusion: B=131072, IN=128 (+bias row -> K=129), OUT=128, RANK=4.
// out[b,o] = bias[o] + sum_r w[r] * prod_m ( factor_m[r,0,o] + sum_k x[b,m,k]*factor_m[r,k+1,o] )
// R2: B-fragments staged per-ot into LDS via global_load_lds width=16; MFMA reads LDS.
// R4: double-buffered half-ot pipeline, counted vmcnt, waves_per_eu(2,2) -> ~118 us.
// R5: waves_per_eu(3) cut the UNIFIED (VGPR+AGPR) budget to ~170 < the ~180 live ->
//     scratch-spilled a[] (FETCH 110->945 MB, WRITE 147->453 MB, main 118->445 us).
//     Model that now fits every round: arch VGPR 84 + a[] in/near AGPR ~ 180 unified
//     -> 2 waves/SIMD (the constant 25% occupancy), and R4's 118 us == 1.6 GB of per-ot
//     x-rematerialization traffic at ~13.6 TB/s out of L3 (x is L3-resident, hence the
//     low HBM FETCH). R4 was L3-BW-bound on remat, not stall-bound.
// R6: (a) waves_per_eu back to (2,2) -- budget 256, no spill (undo R5's trigger).
//     (b) a[] pinned into AGPRs ("+a"), re-pinned at each ot-iteration top: AGPRs have no
//         other consumer here, so the allocator has zero pressure to evict; kills the
//         per-ot x remat (and with it the 1.6 GB L3 stream + its vmcnt-ledger pollution).
//     (c) ISSUE(0,*) after the x-prologue (compiler x-waits would drain the prefetch).
//     Ledger unchanged from R5 (re-verified by induction; 6 loads/half-group, 16 stores/ot;
//     waits only ever over-retire -- safe -- and never retire a store).

typedef _Float16 half8 __attribute__((ext_vector_type(8)));
typedef float f32x4 __attribute__((ext_vector_type(4)));

#define NB 131072L
#define OUT_OFF (NB * 128L)

static __device__ inline f32x4 splat4(float s) { return (f32x4){s, s, s, s}; }
#define CFENCE() asm volatile("" ::: "memory")

// ---------------- prep: pack factors (fp32, [r,129,128]) into f16 MFMA-B fragments ----
// packed frag index: ((m*4 + r)*8 + ot)*4 + ks ; within frag: lane-major, 8 halfs/lane.
// B-frag lane mapping (16x16x32): n = lane&15, k = (lane>>4)*8 + j  (factor row = k+1).
__global__ void pack_b_kernel(const float* __restrict__ af, const float* __restrict__ vf,
                              const float* __restrict__ tf, _Float16* __restrict__ bpk) {
  int t = blockIdx.x * 256 + threadIdx.x;  // [0, 24576)
  int l = t & 63;
  int ks = (t >> 6) & 3;
  int ot = (t >> 8) & 7;
  int r = (t >> 11) & 3;
  int m = t >> 13;
  const float* f = (m == 0) ? af : ((m == 1) ? vf : tf);
  int i0 = 1 + ks * 32 + (l >> 4) * 8;
  int o = ot * 16 + (l & 15);
  half8 v;
#pragma unroll
  for (int j = 0; j < 8; ++j) v[j] = (_Float16)f[(r * 129 + i0 + j) * 128 + o];
  *(half8*)(bpk + (size_t)t * 8) = v;
}

// issue one half-group: 6 regions i = mod*4 + 2h + rr (il = mod*2 + rr), 4 KB each,
// block covers each region in one pass; LDS dst = wave-uniform base + lane*16 (HW layout).
#define ISSUE(ot_, h_)                                                                     \
  do {                                                                                     \
    _Pragma("unroll") for (int il = 0; il < 6; ++il) {                                     \
      const int i_ = (il >> 1) * 4 + 2 * (h_) + (il & 1);                                  \
      const _Float16* gp = bpk + (size_t)(((i_ * 8 + (ot_)) * 2048) + wv * 512 + lane * 8);\
      _Float16* lp = bl + ((h_)*12288 + il * 2048 + wv * 512 + lane * 8);                  \
      __builtin_amdgcn_global_load_lds((const __attribute__((address_space(1))) void*)gp,  \
                                       (__attribute__((address_space(3))) void*)lp, 16, 0, \
                                       0);                                                 \
    }                                                                                      \
  } while (0)

// compute one half: ranks r = 2h, 2h+1 fully (all 3 mods), products folded into oacc
#define COMPUTE_HALF(h_)                                                                   \
  do {                                                                                     \
    _Pragma("unroll") for (int rr = 0; rr < 2; ++rr) {                                     \
      const int r_ = 2 * (h_) + rr;                                                        \
      f32x4 acc[3][2];                                                                     \
      _Pragma("unroll") for (int mod = 0; mod < 3; ++mod) {                                \
        acc[mod][0] = splat4((float)bias_h[mod * 512 + r_ * 128 + ocol]);                  \
        acc[mod][1] = acc[mod][0];                                                         \
      }                                                                                    \
      __builtin_amdgcn_s_setprio(1);                                                       \
      _Pragma("unroll") for (int mod = 0; mod < 3; ++mod) {                                \
        const _Float16* bb = bl + (h_)*12288 + (mod * 2 + rr) * 2048 + lane * 8;           \
        _Pragma("unroll") for (int ks = 0; ks < 4; ++ks) {                                 \
          half8 bf = *(const half8*)(bb + ks * 512); /* ds_read_b128, conflict-free */     \
          acc[mod][0] =                                                                    \
              __builtin_amdgcn_mfma_f32_16x16x32_f16(a[0][mod][ks], bf, acc[mod][0], 0, 0, \
                                                     0);                                   \
          acc[mod][1] =                                                                    \
              __builtin_amdgcn_mfma_f32_16x16x32_f16(a[1][mod][ks], bf, acc[mod][1], 0, 0, \
                                                     0);                                   \
        }                                                                                  \
      }                                                                                    \
      __builtin_amdgcn_s_setprio(0);                                                       \
      _Pragma("unroll") for (int mt = 0; mt < 2; ++mt) {                                   \
        _Pragma("unroll") for (int g = 0; g < 4; ++g) {                                    \
          oacc[mt][g] += wr[r_] * (acc[0][mt][g] * acc[1][mt][g] * acc[2][mt][g]);         \
        }                                                                                  \
      }                                                                                    \
    }                                                                                      \
  } while (0)

// pin all 24 A-fragments into AGPRs (home class anchor; no other AGPR consumers exist)
#define PIN_A()                                                                            \
  do {                                                                                     \
    _Pragma("unroll") for (int mt_ = 0; mt_ < 2; ++mt_)                                    \
        _Pragma("unroll") for (int mod_ = 0; mod_ < 3; ++mod_)                             \
            _Pragma("unroll") for (int ks_ = 0; ks_ < 4; ++ks_)                            \
                asm volatile("" : "+a"(a[mt_][mod_][ks_]));                                \
  } while (0)

// ---------------- main fused kernel -------------------------------------------------
// grid: 1024 blocks x 256 threads; wave W = blockIdx*4 + (tid>>6) owns rows [W*32, W*32+32)
__global__ __launch_bounds__(256) __attribute__((amdgpu_waves_per_eu(2, 2))) void lmf_main(
    const float* __restrict__ x, const float* __restrict__ af, const float* __restrict__ vf,
    const float* __restrict__ tf, const float* __restrict__ fw, const float* __restrict__ fb,
    const _Float16* __restrict__ bpk, float* __restrict__ out) {
  __shared__ _Float16 bl[2 * 12288];  // 2 x 24 KB: buf h holds ranks {2h, 2h+1} of one ot
  __shared__ _Float16 bias_h[1536];   // factor bias rows, f16: [mod*512 + r*128 + o]
  __shared__ float fb_l[128];         // fusion bias, kept f32

  const int lane = threadIdx.x & 63;
  const int wv = threadIdx.x >> 6;
  const int W = blockIdx.x * 4 + wv;
  const long row0 = (long)W * 32;
  const int m16 = lane & 15;  // A row within tile / C col
  const int q = lane >> 4;    // k-octet selector / C row-quad

  // ---- one-time bias staging (loop body then reads LDS only: no stray VMEM in ledger) ----
  for (int idx = threadIdx.x; idx < 1536; idx += 256) {
    const int mod = idx >> 9, rem = idx & 511;
    const float* f = (mod == 0) ? af : ((mod == 1) ? vf : tf);
    bias_h[idx] = (_Float16)f[(rem >> 7) * 16512 + (rem & 127)];
  }
  if (threadIdx.x < 128) fb_l[threadIdx.x] = fb[threadIdx.x];
  __syncthreads();  // full drain: ledger starts clean

  // ---- A fragments: a[mt][mod][ks], 8 halfs each (96 regs), fp32->fp16 RTN ----
  half8 a[2][3][4];
#pragma unroll
  for (int mt = 0; mt < 2; ++mt) {
    const float* xs = x + (row0 + mt * 16 + m16) * 384 + q * 8;
#pragma unroll
    for (int mod = 0; mod < 3; ++mod) {
#pragma unroll
      for (int ks = 0; ks < 4; ++ks) {
        const float* p = xs + mod * 128 + ks * 32;
        f32x4 p0 = __builtin_nontemporal_load((const f32x4*)p);
        f32x4 p1 = __builtin_nontemporal_load((const f32x4*)(p + 4));
#pragma unroll
        for (int j = 0; j < 4; ++j) {
          a[mt][mod][ks][j] = (_Float16)p0[j];
          a[mt][mod][ks][4 + j] = (_Float16)p1[j];
        }
      }
    }
  }
  PIN_A();  // a[] now lives in AGPRs: no spill pressure, no remat from x

  const float wr[4] = {fw[0], fw[1], fw[2], fw[3]};  // wave-uniform -> SGPRs

  float* po0 = out + (row0 + q * 4) * 128 + m16;       // mt=0, copy 0
  float* po1 = out + (row0 + 16 + q * 4) * 128 + m16;  // mt=1, copy 0
  float* qo0 = po0 + OUT_OFF;                          // copy 1
  float* qo1 = po1 + OUT_OFF;

  // ---- pipeline prologue: exactly 12 gload_lds outstanding at loop entry ----
  CFENCE();
  ISSUE(0, 0);
  ISSUE(0, 1);
  CFENCE();

#pragma unroll 1
  for (int ot = 0; ot < 8; ++ot) {
    PIN_A();  // re-anchor home class across the backedge (R3 lesson: one pin isn't binding)
    const int ocol = ot * 16 + m16;

    // ================= half 0 : ranks 0,1 (buf 0) =================
    if (ot == 0) {
      asm volatile("s_waitcnt vmcnt(6)" ::: "memory");  // retire L(0,0); L(0,1) in flight
    } else {
      asm volatile("s_waitcnt vmcnt(22)" ::: "memory");  // retires through L(ot,0)
    }
    __builtin_amdgcn_s_barrier();  // all waves' buf0 quarters landed
    CFENCE();
    f32x4 oacc[2];
    oacc[0] = splat4(fb_l[ocol]);
    oacc[1] = oacc[0];
    COMPUTE_HALF(0);
    CFENCE();
    __builtin_amdgcn_s_barrier();  // all waves done reading buf0
    CFENCE();
    if (ot < 7) ISSUE(ot + 1, 0);  // overwrite buf0 with next ot's r{0,1}

    // ================= half 1 : ranks 2,3 (buf 1) =================
    if (ot == 0) {
      asm volatile("s_waitcnt vmcnt(6)" ::: "memory");  // retire L(0,1); L(1,0) in flight
    } else if (ot < 7) {
      asm volatile("s_waitcnt vmcnt(22)" ::: "memory");  // retires through L(ot,1)
    } else {
      asm volatile("s_waitcnt vmcnt(16)" ::: "memory");  // [L(7,1)6, S(6)16]: retire L(7,1)
    }
    __builtin_amdgcn_s_barrier();
    CFENCE();
    COMPUTE_HALF(1);
    CFENCE();
    __builtin_amdgcn_s_barrier();  // all waves done reading buf1
    CFENCE();
    if (ot < 7) ISSUE(ot + 1, 1);  // overwrite buf1 with next ot's r{2,3}

    // stores AFTER the re-issue: they enter the ledger newest; no wait retires them.
    // C/D layout: col = lane&15, row = q*4 + g
#pragma unroll
    for (int g = 0; g < 4; ++g) {
      __builtin_nontemporal_store(oacc[0][g], po0 + ot * 16 + g * 128);
      __builtin_nontemporal_store(oacc[1][g], po1 + ot * 16 + g * 128);
      __builtin_nontemporal_store(oacc[0][g], qo0 + ot * 16 + g * 128);
      __builtin_nontemporal_store(oacc[1][g], qo1 + ot * 16 + g * 128);
    }
    CFENCE();
  }
}

// ---------------- fallback (only if d_ws is too small): correct fp32 vector version --
__global__ void lmf_fallback(const float* __restrict__ x, const float* __restrict__ af,
                             const float* __restrict__ vf, const float* __restrict__ tf,
                             const float* __restrict__ fw, const float* __restrict__ fb,
                             float* __restrict__ out) {
  long b = blockIdx.x;
  int o = threadIdx.x;  // 128 threads
  __shared__ float xr[384];
  for (int i = threadIdx.x; i < 384; i += 128) xr[i] = x[b * 384 + i];
  __syncthreads();
  float acc = fb[o];
  for (int r = 0; r < 4; ++r) {
    const float* A = af + (long)r * 16512 + o;
    const float* V = vf + (long)r * 16512 + o;
    const float* T = tf + (long)r * 16512 + o;
    float sa = A[0], sv = V[0], st = T[0];
    for (int i = 0; i < 128; ++i) {
      sa += xr[i] * A[(i + 1) * 128];
      sv += xr[128 + i] * V[(i + 1) * 128];
      st += xr[256 + i] * T[(i + 1) * 128];
    }
    acc += fw[r] * sa * sv * st;
  }
  out[b * 128 + o] = acc;
  out[OUT_OFF + b * 128 + o] = acc;
}

extern "C" void kernel_launch(void* const* d_in, const int* in_sizes, int n_in, void* d_out,
                              int out_size, void* d_ws, size_t ws_size, hipStream_t stream) {
  const float* x = (const float*)d_in[0];
  const float* af = (const float*)d_in[1];
  const float* vf = (const float*)d_in[2];
  const float* tf = (const float*)d_in[3];
  const float* fw = (const float*)d_in[4];
  const float* fb = (const float*)d_in[5];
  float* out = (float*)d_out;

  const size_t need = 24576 * 8 * sizeof(_Float16);  // 384 KiB packed B
  if (ws_size >= need) {
    pack_b_kernel<<<96, 256, 0, stream>>>(af, vf, tf, (_Float16*)d_ws);
    lmf_main<<<1024, 256, 0, stream>>>(x, af, vf, tf, fw, fb, (const _Float16*)d_ws, out);
  } else {
    lmf_fallback<<<dim3(131072), 128, 0, stream>>>(x, af, vf, tf, fw, fb, out);
  }
}

// Round 5
// 375.310 us; speedup vs baseline: 1.7279x; 1.0955x over previous
//
#include <hip/hip_runtime.h>

// low_rank multimodal fusion: B=131072, IN=128 (+bias row -> K=129), OUT=128, RANK=4.
// out[b,o] = bias[o] + sum_r w[r] * prod_m ( factor_m[r,0,o] + sum_k x[b,m,k]*factor_m[r,k+1,o] )
// History: R2-R4 = LDS-staged B + barriered double-buffer pipeline -> stuck at ~118 us:
//   VGPR=84 proved the compiler rematerialized the 96-reg A set from x every ot-tile
//   (1.6 GB of L3 re-reads @ ~13.6 TB/s == the whole runtime). R5 (waves_per_eu(3)) and
//   R6 (AGPR pins) both forced spills instead (FETCH/WRITE blowups, 445/172 us).
// R7: remove the structure that makes remat attractive. B (384 KB packed) is L2-hot on
//   every XCD by construction -> read B-fragments DIRECTLY from global (L2) per MFMA:
//   no LDS, no barriers, no vmcnt ledger. ot-loop fully unrolled -> A liveness is one
//   straight-line region (no backedge => no remat incentive); waves_per_eu(2,2) keeps the
//   256-reg budget (A 96 + acc 24 + oacc 8 + in-flight B + addr ~ 200 < 256, no spill).
//   Each wave is an independent stream: x read exactly once from HBM, 768 MFMAs fed from
//   L2, outputs streamed out. Roofline: max(L2 1.6GB ~46us, HBM 335MB ~53us, MFMA 26us).

typedef _Float16 half8 __attribute__((ext_vector_type(8)));
typedef float f32x4 __attribute__((ext_vector_type(4)));

#define NB 131072L
#define OUT_OFF (NB * 128L)

static __device__ inline f32x4 splat4(float s) { return (f32x4){s, s, s, s}; }

// ---------------- prep: pack factors (fp32, [r,129,128]) into f16 MFMA-B fragments ----
// packed frag index: ((m*4 + r)*8 + ot)*4 + ks ; within frag: lane-major, 8 halfs/lane.
// B-frag lane mapping (16x16x32): n = lane&15, k = (lane>>4)*8 + j  (factor row = k+1).
__global__ void pack_b_kernel(const float* __restrict__ af, const float* __restrict__ vf,
                              const float* __restrict__ tf, _Float16* __restrict__ bpk) {
  int t = blockIdx.x * 256 + threadIdx.x;  // [0, 24576)
  int l = t & 63;
  int ks = (t >> 6) & 3;
  int ot = (t >> 8) & 7;
  int r = (t >> 11) & 3;
  int m = t >> 13;
  const float* f = (m == 0) ? af : ((m == 1) ? vf : tf);
  int i0 = 1 + ks * 32 + (l >> 4) * 8;
  int o = ot * 16 + (l & 15);
  half8 v;
#pragma unroll
  for (int j = 0; j < 8; ++j) v[j] = (_Float16)f[(r * 129 + i0 + j) * 128 + o];
  *(half8*)(bpk + (size_t)t * 8) = v;
}

// ---------------- main fused kernel -------------------------------------------------
// grid: 1024 blocks x 256 threads; wave W = blockIdx*4 + (tid>>6) owns rows [W*32, W*32+32)
// No LDS, no barriers: occupancy is register-limited (2 waves/SIMD), latency hidden by
// per-wave ILP (6 independent MFMA chains; 12 B-loads in flight per rank-step).
__global__ __launch_bounds__(256) __attribute__((amdgpu_waves_per_eu(2, 2))) void lmf_main(
    const float* __restrict__ x, const float* __restrict__ af, const float* __restrict__ vf,
    const float* __restrict__ tf, const float* __restrict__ fw, const float* __restrict__ fb,
    const _Float16* __restrict__ bpk, float* __restrict__ out) {
  const int lane = threadIdx.x & 63;
  const int wv = threadIdx.x >> 6;
  const long W = (long)blockIdx.x * 4 + wv;
  const long row0 = W * 32;
  const int m16 = lane & 15;  // A row within tile / C col
  const int q = lane >> 4;    // k-octet selector / C row-quad

  // ---- A fragments: a[mt][mod][ks], 8 halfs each (96 VGPRs), fp32->fp16 RTN ----
  half8 a[2][3][4];
#pragma unroll
  for (int mt = 0; mt < 2; ++mt) {
    const float* xs = x + (row0 + mt * 16 + m16) * 384 + q * 8;
#pragma unroll
    for (int mod = 0; mod < 3; ++mod) {
#pragma unroll
      for (int ks = 0; ks < 4; ++ks) {
        const float* p = xs + mod * 128 + ks * 32;
        f32x4 p0 = __builtin_nontemporal_load((const f32x4*)p);
        f32x4 p1 = __builtin_nontemporal_load((const f32x4*)(p + 4));
#pragma unroll
        for (int j = 0; j < 4; ++j) {
          a[mt][mod][ks][j] = (_Float16)p0[j];
          a[mt][mod][ks][4 + j] = (_Float16)p1[j];
        }
      }
    }
  }

  const float wr[4] = {fw[0], fw[1], fw[2], fw[3]};  // wave-uniform -> SGPRs

  float* po0 = out + (row0 + q * 4) * 128 + m16;       // mt=0, copy 0
  float* po1 = out + (row0 + 16 + q * 4) * 128 + m16;  // mt=1, copy 0
  float* qo0 = po0 + OUT_OFF;                          // copy 1
  float* qo1 = po1 + OUT_OFF;

  const _Float16* bp = bpk + lane * 8;  // per-lane base; frag offsets are compile-time

  // ---- fully unrolled: 8 ot x 4 r x 3 mod x 4 ks; straight-line => A stays resident ----
#pragma unroll
  for (int ot = 0; ot < 8; ++ot) {
    const int ocol = ot * 16 + m16;
    f32x4 oacc[2];
    oacc[0] = splat4(fb[ocol]);  // L2-hot scalar gather
    oacc[1] = oacc[0];
#pragma unroll
    for (int r = 0; r < 4; ++r) {
      // bias-row of each factor folded in as MFMA C-init (per-lane col-dependent, L2-hot)
      f32x4 acc[3][2];
      acc[0][0] = splat4(af[r * 16512 + ocol]);
      acc[1][0] = splat4(vf[r * 16512 + ocol]);
      acc[2][0] = splat4(tf[r * 16512 + ocol]);
      acc[0][1] = acc[0][0];
      acc[1][1] = acc[1][0];
      acc[2][1] = acc[2][0];
      // load this rank's 12 B-frags first (independent dwordx4 stream, L2-hot),
      // then the 24 MFMAs; compiler interleaves across ranks/ots for latency hiding.
      half8 bf[3][4];
#pragma unroll
      for (int mod = 0; mod < 3; ++mod) {
        const _Float16* bb = bp + (size_t)((((mod * 4 + r) * 8 + ot) * 4) * 512);
#pragma unroll
        for (int ks = 0; ks < 4; ++ks) bf[mod][ks] = *(const half8*)(bb + ks * 512);
      }
#pragma unroll
      for (int mod = 0; mod < 3; ++mod) {
#pragma unroll
        for (int ks = 0; ks < 4; ++ks) {
          acc[mod][0] = __builtin_amdgcn_mfma_f32_16x16x32_f16(a[0][mod][ks], bf[mod][ks],
                                                               acc[mod][0], 0, 0, 0);
          acc[mod][1] = __builtin_amdgcn_mfma_f32_16x16x32_f16(a[1][mod][ks], bf[mod][ks],
                                                               acc[mod][1], 0, 0, 0);
        }
      }
#pragma unroll
      for (int mt = 0; mt < 2; ++mt) {
#pragma unroll
        for (int g = 0; g < 4; ++g) {
          oacc[mt][g] += wr[r] * (acc[0][mt][g] * acc[1][mt][g] * acc[2][mt][g]);
        }
      }
    }
    // C/D layout: col = lane&15, row = q*4 + g
#pragma unroll
    for (int g = 0; g < 4; ++g) {
      __builtin_nontemporal_store(oacc[0][g], po0 + ot * 16 + g * 128);
      __builtin_nontemporal_store(oacc[1][g], po1 + ot * 16 + g * 128);
      __builtin_nontemporal_store(oacc[0][g], qo0 + ot * 16 + g * 128);
      __builtin_nontemporal_store(oacc[1][g], qo1 + ot * 16 + g * 128);
    }
  }
}

// ---------------- fallback (only if d_ws is too small): correct fp32 vector version --
__global__ void lmf_fallback(const float* __restrict__ x, const float* __restrict__ af,
                             const float* __restrict__ vf, const float* __restrict__ tf,
                             const float* __restrict__ fw, const float* __restrict__ fb,
                             float* __restrict__ out) {
  long b = blockIdx.x;
  int o = threadIdx.x;  // 128 threads
  __shared__ float xr[384];
  for (int i = threadIdx.x; i < 384; i += 128) xr[i] = x[b * 384 + i];
  __syncthreads();
  float acc = fb[o];
  for (int r = 0; r < 4; ++r) {
    const float* A = af + (long)r * 16512 + o;
    const float* V = vf + (long)r * 16512 + o;
    const float* T = tf + (long)r * 16512 + o;
    float sa = A[0], sv = V[0], st = T[0];
    for (int i = 0; i < 128; ++i) {
      sa += xr[i] * A[(i + 1) * 128];
      sv += xr[128 + i] * V[(i + 1) * 128];
      st += xr[256 + i] * T[(i + 1) * 128];
    }
    acc += fw[r] * sa * sv * st;
  }
  out[b * 128 + o] = acc;
  out[OUT_OFF + b * 128 + o] = acc;
}

extern "C" void kernel_launch(void* const* d_in, const int* in_sizes, int n_in, void* d_out,
                              int out_size, void* d_ws, size_t ws_size, hipStream_t stream) {
  const float* x = (const float*)d_in[0];
  const float* af = (const float*)d_in[1];
  const float* vf = (const float*)d_in[2];
  const float* tf = (const float*)d_in[3];
  const float* fw = (const float*)d_in[4];
  const float* fb = (const float*)d_in[5];
  float* out = (float*)d_out;

  const size_t need = 24576 * 8 * sizeof(_Float16);  // 384 KiB packed B
  if (ws_size >= need) {
    pack_b_kernel<<<96, 256, 0, stream>>>(af, vf, tf, (_Float16*)d_ws);
    lmf_main<<<1024, 256, 0, stream>>>(x, af, vf, tf, fw, fb, (const _Float16*)d_ws, out);
  } else {
    lmf_fallback<<<dim3(131072), 128, 0, stream>>>(x, af, vf, tf, fw, fb, out);
  }
}